// Round 2
// baseline (231.622 us; speedup 1.0000x reference)
//
#include <hip/hip_runtime.h>
#include <math.h>

#define CC 64
#define KK 48
#define HH 4
#define DD 16
#define FF 256

// ws layout (floats):
//   0      wqT   [64][64]   wqT[j*64+c] = wq[c][j]
//   4096   wvT   [64][64]
//   8192   opT   [64][64]
//   12288  l1T   [64][256]  l1T[c*256+f] = lin1_w[f][c]
//   28672  l2T   [256][64]  l2T[f*64+c]  = lin2_w[c][f]
//   45056  oT    [64][64]   oT[c*64+co]  = out_w[co][c]
//   49152  nrm   s[64], t[64]
//   49280  bn2   s[64], t[64]
//   49408  mask-format flag (int: 1 = uint8 bool, 0 = int32 bool)
#define WS_FLAG 49408

// ---------------- mask dtype detection ----------------
// int32-bool buffer: bytes at i%4!=0 are ALWAYS zero (values are 0/1).
// uint8-bool buffer: ~30% of all bytes are 1. Sample 4 KB -> certain.
__global__ __launch_bounds__(256) void detect_mask_kernel(
    const unsigned char* __restrict__ km, int* __restrict__ flag)
{
  int any = 0;
  for (int i = threadIdx.x; i < 4096; i += 256)
    if ((i & 3) && km[i]) any = 1;
  __shared__ int s;
  if (threadIdx.x == 0) s = 0;
  __syncthreads();
  if (any) atomicOr(&s, 1);
  __syncthreads();
  if (threadIdx.x == 0) *flag = s;
}

// ---------------- prep: transposes + BN folds into d_ws ----------------
__global__ __launch_bounds__(256) void prep_kernel(
    const float* __restrict__ ipw, const float* __restrict__ opw,
    const float* __restrict__ l1w, const float* __restrict__ l2w,
    const float* __restrict__ ow,
    const float* __restrict__ ng, const float* __restrict__ nb,
    const float* __restrict__ nm, const float* __restrict__ nv,
    const float* __restrict__ b2g, const float* __restrict__ b2b,
    const float* __restrict__ b2m, const float* __restrict__ b2v,
    float* __restrict__ ws)
{
  int t = blockIdx.x * 256 + threadIdx.x;
  float* wqT = ws;
  float* wvT = ws + 4096;
  float* opT = ws + 8192;
  float* l1T = ws + 12288;
  float* l2T = ws + 28672;
  float* oT  = ws + 45056;
  float* nrm = ws + 49152;
  float* bn2 = ws + 49280;
  if (t < 4096)       { int j = t >> 6, c = t & 63; wqT[t] = ipw[c * CC + j]; }
  else if (t < 8192)  { int i = t - 4096;  int j = i >> 6, c = i & 63; wvT[i] = ipw[(2 * CC + c) * CC + j]; }
  else if (t < 12288) { int i = t - 8192;  int j = i >> 6, c = i & 63; opT[i] = opw[c * CC + j]; }
  else if (t < 28672) { int i = t - 12288; int c = i >> 8, f = i & 255; l1T[i] = l1w[f * CC + c]; }
  else if (t < 45056) { int i = t - 28672; int f = i >> 6, c = i & 63; l2T[i] = l2w[c * FF + f]; }
  else if (t < 49152) { int i = t - 45056; int c = i >> 6, co = i & 63; oT[i] = ow[co * CC + c]; }
  else if (t < 49216) { int c = t - 49152; float s = ng[c] / sqrtf(nv[c] + 1e-5f); nrm[c] = s; nrm[64 + c] = nb[c] - nm[c] * s; }
  else if (t < 49280) { int c = t - 49216; float s = b2g[c] / sqrtf(b2v[c] + 1e-5f); bn2[c] = s; bn2[64 + c] = b2b[c] - b2m[c] * s; }
}

// ---------------- attention: one wave (64 threads) per query ----------------
__global__ __launch_bounds__(64) void attn_kernel(
    const float* __restrict__ vfeat, const float* __restrict__ vcoord,
    const float* __restrict__ qcoord, const int* __restrict__ kidx,
    const unsigned char* __restrict__ km8, const int* __restrict__ km32,
    const int* __restrict__ maskfmt,
    const float* __restrict__ qpw, const float* __restrict__ qpb,
    const float* __restrict__ kpw, const float* __restrict__ kpb,
    const float* __restrict__ ipw, const float* __restrict__ ipb,
    const float* __restrict__ opb,
    const float* __restrict__ wqT, const float* __restrict__ wvT,
    const float* __restrict__ opT,
    float* __restrict__ attend)
{
  const int m = blockIdx.x;
  const int tid = threadIdx.x;

  __shared__ float s_kin[KK][68];   // pad 68: 16B-aligned rows
  __shared__ float s_rel[KK][4];
  __shared__ int   s_idx[KK];
  __shared__ unsigned char s_msk[KK];
  __shared__ float s_vec[CC];       // q_in, later reused for o
  __shared__ float s_q[CC];
  __shared__ float s_qw[HH][CC];
  __shared__ float s_qb[HH];
  __shared__ float s_sc[HH][KK];    // scores, then attention weights
  __shared__ float s_t[HH][CC];

  const float qx = qcoord[m * 3 + 0], qy = qcoord[m * 3 + 1], qz = qcoord[m * 3 + 2];
  const int is_u8 = *maskfmt;

  // q_in[c] = relu(q_pos_w[c]·qc + b)
  {
    float v = qpw[tid * 3 + 0] * qx + qpw[tid * 3 + 1] * qy + qpw[tid * 3 + 2] * qz + qpb[tid];
    s_vec[tid] = fmaxf(v, 0.f);
  }
  if (tid < KK) {
    int idx = kidx[m * KK + tid];
    s_idx[tid] = idx;
    s_rel[tid][0] = vcoord[idx * 3 + 0] - qx;
    s_rel[tid][1] = vcoord[idx * 3 + 1] - qy;
    s_rel[tid][2] = vcoord[idx * 3 + 2] - qz;
    s_msk[tid] = is_u8 ? km8[m * KK + tid]
                       : (unsigned char)(km32[m * KK + tid] != 0);
  }
  __syncthreads();

  // q[c] = (q_in @ wq.T + bq) * d^-0.5
  {
    float acc = ipb[tid];
    #pragma unroll
    for (int j = 0; j < CC; ++j) acc += wqT[j * CC + tid] * s_vec[j];
    s_q[tid] = acc * 0.25f;
  }
  __syncthreads();

  // qw[h][c] = sum_d q[h,d]*wk[h*16+d][c]    (fold q into wk)
  #pragma unroll
  for (int h = 0; h < HH; ++h) {
    float acc = 0.f;
    #pragma unroll
    for (int d = 0; d < DD; ++d)
      acc += s_q[h * DD + d] * ipw[(CC + h * DD + d) * CC + tid];
    s_qw[h][tid] = acc;
  }
  if (tid < HH) {
    float acc = 0.f;
    #pragma unroll
    for (int d = 0; d < DD; ++d) acc += s_q[tid * DD + d] * ipb[CC + tid * DD + d];
    s_qb[tid] = acc;
  }

  // k_in[k][c] = vf[idx[k]][c] + relu(k_pos_w[c]·rel[k] + b[c])
  const float kw0 = kpw[tid * 3 + 0], kw1 = kpw[tid * 3 + 1], kw2 = kpw[tid * 3 + 2], kb = kpb[tid];
  #pragma unroll 8
  for (int k = 0; k < KK; ++k) {
    float pos = kw0 * s_rel[k][0] + kw1 * s_rel[k][1] + kw2 * s_rel[k][2] + kb;
    pos = fmaxf(pos, 0.f);
    s_kin[k][tid] = vfeat[(size_t)s_idx[k] * CC + tid] + pos;
  }
  __syncthreads();

  // scores: s[h][k] = qw[h]·k_in[k] + qb[h]   (thread k)
  if (tid < KK) {
    float sc[HH];
    #pragma unroll
    for (int h = 0; h < HH; ++h) sc[h] = s_qb[h];
    if (s_msk[tid]) {
      #pragma unroll
      for (int h = 0; h < HH; ++h) sc[h] = -1e9f;
    } else {
      const float4* kin4 = reinterpret_cast<const float4*>(&s_kin[tid][0]);
      #pragma unroll
      for (int c4 = 0; c4 < 16; ++c4) {
        float4 kv = kin4[c4];
        #pragma unroll
        for (int h = 0; h < HH; ++h) {
          float4 qw4 = *reinterpret_cast<const float4*>(&s_qw[h][c4 * 4]);
          sc[h] += qw4.x * kv.x + qw4.y * kv.y + qw4.z * kv.z + qw4.w * kv.w;
        }
      }
    }
    #pragma unroll
    for (int h = 0; h < HH; ++h) s_sc[h][tid] = sc[h];
  }
  __syncthreads();

  // softmax per head over K (wave-parallel; lanes >= 48 padded with -inf)
  #pragma unroll
  for (int h = 0; h < HH; ++h) {
    float v = (tid < KK) ? s_sc[h][tid] : -INFINITY;
    float mx = v;
    #pragma unroll
    for (int off = 32; off > 0; off >>= 1) mx = fmaxf(mx, __shfl_xor(mx, off, 64));
    float e = expf(v - mx);
    float sum = e;
    #pragma unroll
    for (int off = 32; off > 0; off >>= 1) sum += __shfl_xor(sum, off, 64);
    if (tid < KK) s_sc[h][tid] = e / sum;  // overwrite scores with weights (owner-only)
  }
  __syncthreads();

  // t[h][c] = sum_k a[h][k] * k_in[k][c]   (thread c)
  {
    float tv[HH] = {0.f, 0.f, 0.f, 0.f};
    #pragma unroll 8
    for (int k = 0; k < KK; ++k) {
      float kv = s_kin[k][tid];
      #pragma unroll
      for (int h = 0; h < HH; ++h) tv[h] += s_sc[h][k] * kv;
    }
    #pragma unroll
    for (int h = 0; h < HH; ++h) s_t[h][tid] = tv[h];
  }
  __syncthreads();

  // o[c] = wv[c]·t[h(c)] + bv[c]    (softmax weights sum to 1 -> bv passes through)
  {
    const int hp = tid >> 4;
    float acc = ipb[2 * CC + tid];
    #pragma unroll
    for (int j = 0; j < CC; ++j) acc += wvT[j * CC + tid] * s_t[hp][j];
    s_vec[tid] = acc;
  }
  __syncthreads();

  // attend[c] = out_proj[c]·o + b
  {
    float acc = opb[tid];
    #pragma unroll
    for (int j = 0; j < CC; ++j) acc += opT[j * CC + tid] * s_vec[j];
    attend[(size_t)m * CC + tid] = acc;
  }
}

// ---------------- MLP chain: 32 queries per block, in-place on d_out ----------------
__global__ __launch_bounds__(256) void mlp_kernel(
    float* __restrict__ inout,
    const float* __restrict__ l1T, const float* __restrict__ l1b,
    const float* __restrict__ l2T, const float* __restrict__ l2b,
    const float* __restrict__ oT,  const float* __restrict__ ob,
    const float* __restrict__ nrm, const float* __restrict__ bn2,
    int M)
{
  const int q0 = blockIdx.x * 32;
  const int tid = threadIdx.x;
  __shared__ float s_x[32][68];
  __shared__ float s_h1[32][257];
  const int nq = min(32, M - q0);

  for (int i = tid; i < 32 * 64; i += 256) {
    int q = i >> 6, c = i & 63;
    s_x[q][c] = (q < nq) ? inout[(size_t)(q0 + q) * 64 + c] : 0.f;
  }
  __syncthreads();

  // h1[q][f] = relu(lin1[f]·attend[q] + b)   (thread owns f = tid, weights in regs)
  {
    float w[64];
    #pragma unroll
    for (int c = 0; c < 64; ++c) w[c] = l1T[c * 256 + tid];
    const float bf = l1b[tid];
    for (int q = 0; q < 32; ++q) {
      float acc = bf;
      const float4* a4 = reinterpret_cast<const float4*>(&s_x[q][0]);
      #pragma unroll
      for (int c4 = 0; c4 < 16; ++c4) {
        float4 v = a4[c4];
        acc += w[c4 * 4 + 0] * v.x + w[c4 * 4 + 1] * v.y + w[c4 * 4 + 2] * v.z + w[c4 * 4 + 3] * v.w;
      }
      s_h1[q][tid] = fmaxf(acc, 0.f);
    }
  }
  __syncthreads();

  // x[q][c] = BN(attend + lin2·h1 + b)  — register tile 4c x 2q per thread
  {
    const int cq = tid & 15, qg = tid >> 4;
    const int c0 = cq * 4;
    const int qA = qg * 2, qB = qg * 2 + 1;
    float acc[4][2];
    #pragma unroll
    for (int i = 0; i < 4; ++i) { acc[i][0] = 0.f; acc[i][1] = 0.f; }
    #pragma unroll 4
    for (int f = 0; f < 256; ++f) {
      const float4 w4 = *reinterpret_cast<const float4*>(&l2T[f * 64 + c0]);
      const float hA = s_h1[qA][f];
      const float hB = s_h1[qB][f];
      acc[0][0] += w4.x * hA; acc[0][1] += w4.x * hB;
      acc[1][0] += w4.y * hA; acc[1][1] += w4.y * hB;
      acc[2][0] += w4.z * hA; acc[2][1] += w4.z * hB;
      acc[3][0] += w4.w * hA; acc[3][1] += w4.w * hB;
    }
    #pragma unroll
    for (int i = 0; i < 4; ++i) {
      const int c = c0 + i;
      const float s = nrm[c], t2 = nrm[64 + c], b = l2b[c];
      float xA = s_x[qA][c] + acc[i][0] + b;
      float xB = s_x[qB][c] + acc[i][1] + b;
      s_x[qA][c] = xA * s + t2;   // owner-only in-place update
      s_x[qB][c] = xB * s + t2;
    }
  }
  __syncthreads();

  // y[q][co] = relu(BN2(out_w[co]·x[q] + b))
  {
    const int cq = tid & 15, qg = tid >> 4;
    const int co0 = cq * 4;
    const int qA = qg * 2, qB = qg * 2 + 1;
    float acc[4][2];
    #pragma unroll
    for (int i = 0; i < 4; ++i) { acc[i][0] = 0.f; acc[i][1] = 0.f; }
    #pragma unroll 4
    for (int c = 0; c < 64; ++c) {
      const float4 w4 = *reinterpret_cast<const float4*>(&oT[c * 64 + co0]);
      const float xA = s_x[qA][c];
      const float xB = s_x[qB][c];
      acc[0][0] += w4.x * xA; acc[0][1] += w4.x * xB;
      acc[1][0] += w4.y * xA; acc[1][1] += w4.y * xB;
      acc[2][0] += w4.z * xA; acc[2][1] += w4.z * xB;
      acc[3][0] += w4.w * xA; acc[3][1] += w4.w * xB;
    }
    #pragma unroll
    for (int j = 0; j < 2; ++j) {
      const int q = (j == 0) ? qA : qB;
      if (q < nq) {
        float4 y;
        y.x = fmaxf((acc[0][j] + ob[co0 + 0]) * bn2[co0 + 0] + bn2[64 + co0 + 0], 0.f);
        y.y = fmaxf((acc[1][j] + ob[co0 + 1]) * bn2[co0 + 1] + bn2[64 + co0 + 1], 0.f);
        y.z = fmaxf((acc[2][j] + ob[co0 + 2]) * bn2[co0 + 2] + bn2[64 + co0 + 2], 0.f);
        y.w = fmaxf((acc[3][j] + ob[co0 + 3]) * bn2[co0 + 3] + bn2[64 + co0 + 3], 0.f);
        *reinterpret_cast<float4*>(&inout[(size_t)(q0 + q) * 64 + co0]) = y;
      }
    }
  }
}

extern "C" void kernel_launch(void* const* d_in, const int* in_sizes, int n_in,
                              void* d_out, int out_size, void* d_ws, size_t ws_size,
                              hipStream_t stream) {
  const float* vfeat  = (const float*)d_in[0];
  const float* vcoord = (const float*)d_in[1];
  const float* qcoord = (const float*)d_in[2];
  const int*   kidx   = (const int*)d_in[3];
  const unsigned char* km8  = (const unsigned char*)d_in[4];
  const int*           km32 = (const int*)d_in[4];
  const float* qpw = (const float*)d_in[5];
  const float* qpb = (const float*)d_in[6];
  const float* kpw = (const float*)d_in[7];
  const float* kpb = (const float*)d_in[8];
  const float* ipw = (const float*)d_in[9];
  const float* ipb = (const float*)d_in[10];
  const float* opw = (const float*)d_in[11];
  const float* opb = (const float*)d_in[12];
  const float* l1w = (const float*)d_in[13];
  const float* l1b = (const float*)d_in[14];
  const float* l2w = (const float*)d_in[15];
  const float* l2b = (const float*)d_in[16];
  const float* ng  = (const float*)d_in[17];
  const float* nb  = (const float*)d_in[18];
  const float* nm  = (const float*)d_in[19];
  const float* nv  = (const float*)d_in[20];
  const float* ow  = (const float*)d_in[21];
  const float* ob  = (const float*)d_in[22];
  const float* b2g = (const float*)d_in[23];
  const float* b2b = (const float*)d_in[24];
  const float* b2m = (const float*)d_in[25];
  const float* b2v = (const float*)d_in[26];

  const int M = in_sizes[2] / 3;
  float* ws  = (float*)d_ws;
  float* out = (float*)d_out;
  int* flag = (int*)(ws + WS_FLAG);

  // 0) detect mask dtype (uint8 bool vs int32 bool)
  detect_mask_kernel<<<1, 256, 0, stream>>>(km8, flag);
  // 1) weight transposes + BN folds
  prep_kernel<<<193, 256, 0, stream>>>(ipw, opw, l1w, l2w, ow,
                                       ng, nb, nm, nv, b2g, b2b, b2m, b2v, ws);
  // 2) attention -> attend staged in d_out
  attn_kernel<<<M, 64, 0, stream>>>(vfeat, vcoord, qcoord, kidx, km8, km32, flag,
                                    qpw, qpb, kpw, kpb, ipw, ipb, opb,
                                    ws /*wqT*/, ws + 4096 /*wvT*/, ws + 8192 /*opT*/,
                                    out);
  // 3) FFN + BN + output layer, in place on d_out
  mlp_kernel<<<(M + 31) / 32, 256, 0, stream>>>(out,
                                                ws + 12288, l1b,
                                                ws + 28672, l2b,
                                                ws + 45056, ob,
                                                ws + 49152, ws + 49280, M);
}